// Round 15
// baseline (212.435 us; speedup 1.0000x reference)
//
#include <hip/hip_runtime.h>
#include <hip/hip_bf16.h>

// PointsToBEV round 28. R27 exactly flat (206.74->206.77): grid 768==1024
// for k_mlp (R23 reading was confounded), chHead trim noise. All kernels now
// below top-5 cutoff (only harness re-poison fills visible) -> no per-kernel
// counter visibility. R28 tests the launch-gap hypothesis by cutting a
// dispatch: k_init deleted. cnt+diag zeroing -> one hipMemsetAsync
// (capture-safe; harness uses memsets itself); dtype probes -> per-block
// redundant computation (320/512 L2-hot shorts in each kernel's preamble,
// removes the flags cross-kernel dependency). Everything else frozen.
// Pre-commit: flat again => structure is at its practical fixed point.

#define B_    4
#define NP_   200000
#define CH    80
#define COUT_ 128
#define BEVH  128
#define BEVW  128
#define HW_   (BEVH * BEVW)
#define NCHK  (NP_ / 64)        // 3125 chunks per batch (NP_ % 64 == 0)

// Per-batch bytes: cnt(HW u32) + sums+staging((HW+NCHK)*80 f32) +
// offs(HW u32 +pad) + chHead(NCHK u8) + rank(NP u32) + prec(NP*16)
#define PER_BATCH ((size_t)HW_ * 328 + (size_t)NCHK * 321 + (size_t)NP_ * 20)
#define EXTRA_BYTES 512

#define MAGIC_OFF   128
#define SCRATCH_OFF 256

typedef _Float16 half4_t __attribute__((ext_vector_type(4)));
typedef _Float16 half8_t __attribute__((ext_vector_type(8)));
typedef float    f32x4_t __attribute__((ext_vector_type(4)));
typedef unsigned short ushort8_t __attribute__((ext_vector_type(8)));

#define HSTR 104   // W2T k-stride in f16 (52 dwords -> 2-way banks, free)
#define ESTR 72    // embT pt-stride in f16 (36 dwords -> 2-way banks, free)
#define ESLICE (16 * ESTR)
#define MSTR 104   // sMean k-stride in f16 (16B-aligned, 2-way free)

__device__ __forceinline__ float bf2f(unsigned short u) {
    return __uint_as_float(((unsigned int)u) << 16);
}
__device__ __forceinline__ unsigned short f2h(float f) {
    return __builtin_bit_cast(unsigned short, (_Float16)f);
}
__device__ __forceinline__ float h2f(unsigned short u) {
    return (float)__builtin_bit_cast(_Float16, u);
}

__device__ __forceinline__ int cell_of(float px, float py, int bloc) {
    const int ix = (int)floorf((px + 50.0f) / 0.78125f);
    const int iy = (int)floorf((py + 50.0f) / 0.78125f);
    if (ix < 0 || ix >= BEVW || iy < 0 || iy >= BEVH) return -1;
    return bloc * HW_ + iy * BEVW + ix;
}

// Per-block dtype probe (R28): lanes t<64 scan n shorts as bf16; if the max
// abs value exceeds 1e6 the buffer is f32 reinterpreted (low-halves look
// like huge bf16s). Identical heuristic to the old k_detect, relocated.
// Caller must __syncthreads() after (result in *dst).
__device__ __forceinline__ void probe_f32(const unsigned short* __restrict__ src,
                                          int n, int t, int* __restrict__ dst) {
    if (t < 64) {
        float m = 0.0f;
        for (int i = t; i < n; i += 64) {
            const float a = fabsf(bf2f(src[i]));
            if (a == a) m = fmaxf(m, a);
        }
#pragma unroll
        for (int off = 32; off > 0; off >>= 1)
            m = fmaxf(m, __shfl_down(m, off));
        if (t == 0) *dst = (m > 1.0e6f) ? 1 : 0;
    }
}

// Load 2 consecutive points (p0 even) as one vector op where possible.
__device__ __forceinline__ void load_pt2(const void* pts_raw, size_t pbase,
                                         int pf32, float x[2], float y[2],
                                         float z[2], float w[2]) {
    if (pf32) {
        const float4 a = ((const float4*)pts_raw)[pbase];
        const float4 b = ((const float4*)pts_raw)[pbase + 1];
        x[0] = a.x; y[0] = a.y; z[0] = a.z; w[0] = a.w;
        x[1] = b.x; y[1] = b.y; z[1] = b.z; w[1] = b.w;
    } else {
        const ushort8_t u = ((const ushort8_t*)pts_raw)[pbase >> 1];
        x[0] = bf2f(u[0]); y[0] = bf2f(u[1]); z[0] = bf2f(u[2]); w[0] = bf2f(u[3]);
        x[1] = bf2f(u[4]); y[1] = bf2f(u[5]); z[1] = bf2f(u[6]); w[1] = bf2f(u[7]);
    }
}

// ---------------------------------------------------------------------------
// Phase A: histogram (2 points per thread). atomicAdd's return value is the
// point's within-cell rank -- persisted (coalesced) for the atomic-free
// scatter. Per-block pts-dtype probe (R28).
// ---------------------------------------------------------------------------
__global__ __launch_bounds__(256) void k_bin(
    const void* __restrict__ pts_raw,
    unsigned int* __restrict__ cnt,
    unsigned int* __restrict__ rank,
    int b0, int npts)
{
    __shared__ int sPf32;
    const int t = threadIdx.x;
    probe_f32((const unsigned short*)pts_raw, 512, t, &sPf32);
    __syncthreads();
    const int pf32 = sPf32;

    const int gid = blockIdx.x * 256 + t;
    const int p0 = gid * 2;
    if (p0 >= npts) return;
    const int bloc = p0 / NP_;                 // p0 even, NP_ even: pair same batch
    float x[2], y[2], z[2], w[2];
    load_pt2(pts_raw, (size_t)b0 * NP_ + p0, pf32, x, y, z, w);
#pragma unroll
    for (int k = 0; k < 2; ++k) {
        const int g = cell_of(x[k], y[k], bloc);
        if (g >= 0) rank[p0 + k] = atomicAdd(&cnt[g], 1u);
    }
}

// ---------------------------------------------------------------------------
// Phase B (fused scan): per-block redundant base re-sum (L2-hot, no
// cross-block sync), local scan, offs (+sentinel). chHead fully written
// here: each nonempty cell sets 1 at its start if chunk-aligned, and 0 for
// every chunk boundary strictly inside its span. Spans partition [0, end)
// -> exactly-once coverage, race-free.
// ---------------------------------------------------------------------------
__global__ __launch_bounds__(256) void k_scan(
    const unsigned int* __restrict__ cnt,
    unsigned int* __restrict__ offs,
    unsigned char* __restrict__ chHead,
    int nblocks, int n)
{
    __shared__ unsigned int sd[256];
    __shared__ unsigned int sBase;
    const int t = threadIdx.x;
    const int blk = blockIdx.x;
    const int i0 = blk * 1024 + t * 4;
    const unsigned int c0 = cnt[i0], c1 = cnt[i0 + 1],
                       c2 = cnt[i0 + 2], c3 = cnt[i0 + 3];
    const unsigned int s4 = c0 + c1 + c2 + c3;

    unsigned int bsum = 0;
    const int q4 = blk << 8;
    const uint4* cnt4 = (const uint4*)cnt;
    for (int i = t; i < q4; i += 256) {
        const uint4 v = cnt4[i];
        bsum += v.x + v.y + v.z + v.w;
    }
    sd[t] = bsum;
    __syncthreads();
    for (int d = 128; d > 0; d >>= 1) {
        if (t < d) sd[t] += sd[t + d];
        __syncthreads();
    }
    if (t == 0) sBase = sd[0];
    __syncthreads();

    sd[t] = s4;
    __syncthreads();
    for (int d = 1; d < 256; d <<= 1) {
        const unsigned int add = (t >= d) ? sd[t - d] : 0u;
        __syncthreads();
        sd[t] += add;
        __syncthreads();
    }
    unsigned int run = sBase + sd[t] - s4;    // exclusive prefix
    const unsigned int cs[4] = {c0, c1, c2, c3};
#pragma unroll
    for (int j = 0; j < 4; ++j) {
        offs[i0 + j] = run;
        const unsigned int c = cs[j];
        if (c) {
            if (!(run & 63u)) chHead[run >> 6] = 1;
            const unsigned int bA = (run >> 6) + 1;
            const unsigned int bB = (run + c - 1) >> 6;
            for (unsigned int b = bA; b <= bB; ++b) chHead[b] = 0;
        }
        run += c;
    }
    if (blk == nblocks - 1 && t == 255) offs[n] = run;
}

// ---------------------------------------------------------------------------
// Phase C: atomic-free scatter, 4 points/thread. pos = offs[g] + rank[p];
// all chains independent. rec = {dx|dy, z|w (fp16), g, 0}. Per-block probe.
// ---------------------------------------------------------------------------
__global__ __launch_bounds__(256) void k_scatteridx(
    const void* __restrict__ pts_raw,
    const unsigned int* __restrict__ offs,
    const unsigned int* __restrict__ rank,
    uint4* __restrict__ prec,
    int b0, int npts)
{
    __shared__ int sPf32;
    const int t = threadIdx.x;
    probe_f32((const unsigned short*)pts_raw, 512, t, &sPf32);
    __syncthreads();
    const int pf32 = sPf32;

    const int gid = blockIdx.x * 256 + t;
    const int p0 = gid * 4;
    if (p0 >= npts) return;
    const int bloc = p0 / NP_;                 // NP_ % 4 == 0: quad same batch
    float x[4], y[4], z[4], w[4];
    load_pt2(pts_raw, (size_t)b0 * NP_ + p0, pf32, x, y, z, w);
    load_pt2(pts_raw, (size_t)b0 * NP_ + p0 + 2, pf32, x + 2, y + 2,
             z + 2, w + 2);
    const uint4 rk = *(const uint4*)&rank[p0];
    const unsigned int rks[4] = {rk.x, rk.y, rk.z, rk.w};

    int g4[4];
#pragma unroll
    for (int k = 0; k < 4; ++k)
        g4[k] = cell_of(x[k], y[k], bloc);

#pragma unroll
    for (int k = 0; k < 4; ++k) {
        const int g = g4[k];
        if (g < 0) continue;
        const unsigned int pos = offs[g] + rks[k];
        const int cellin = g & (HW_ - 1);
        const float cx = fmaf((float)(cellin & 127), 0.78125f, -49.609375f);
        const float cy = fmaf((float)(cellin >> 7), 0.78125f, -49.609375f);
        uint4 r;
        r.x = (unsigned int)f2h(x[k] - cx) | ((unsigned int)f2h(y[k] - cy) << 16);
        r.y = (unsigned int)f2h(z[k]) | ((unsigned int)f2h(w[k]) << 16);
        r.z = (unsigned int)g;
        r.w = 0u;
        prec[pos] = r;
    }
}

// ---------------------------------------------------------------------------
// Phase D (persistent MFMA): waves grid-stride over 64-point chunks.
// 16B records: 4 gather loads/lane, own-g = gm[quad]. Next-chunk prefetch.
// Fast path: 2-slice embT pipeline hides the per-nt LDS round-trip.
// Per-block W1-dtype probe (R28).
// ---------------------------------------------------------------------------
__global__ __launch_bounds__(256, 2) void k_mlp_mfma(
    const uint4* __restrict__ precs,
    const void* __restrict__ W1_raw,
    const void* __restrict__ b1_raw,
    const void* __restrict__ W2_raw,
    const void* __restrict__ b2_raw,
    unsigned int* __restrict__ magic,
    const unsigned int* __restrict__ offs,    // ncells+1 (sentinel = total)
    const unsigned char* __restrict__ chHead,
    float* __restrict__ sums,                 // 5 planes of P floats
    int ncells, int P)
{
    __shared__ float sW1[4 * CH];             // [f][k]
    __shared__ float sb1[CH];
    __shared__ float sb2f[CH];
    __shared__ _Float16 sW2T[80 * HSTR];      // [ch_out][k], k 80..103 zero
    __shared__ _Float16 sEmb[4][2 * ESLICE];  // per-wave 2-slice embT dbuf
    __shared__ unsigned int sCellG[4][64];
    __shared__ int sWf32;

    const int t = threadIdx.x;
    probe_f32((const unsigned short*)W1_raw, 320, t, &sWf32);
    __syncthreads();
    const int wf32 = sWf32;

    // ---- staging (W2 read coalesced, LDS-scatter write).
    if (wf32) {
        const float* W1 = (const float*)W1_raw;
        const float* b1 = (const float*)b1_raw;
        const float* b2 = (const float*)b2_raw;
        for (int i = t; i < 4 * CH; i += 256) sW1[i] = W1[i];
        if (t < CH) { sb1[t] = b1[t]; sb2f[t] = b2[t]; }
        const float* W2 = (const float*)W2_raw;
        for (int i = t; i < CH * CH; i += 256)      // i = c*80 + d, coalesced
            sW2T[(i % CH) * HSTR + i / CH] = (_Float16)W2[i];
    } else {
        const unsigned short* W1 = (const unsigned short*)W1_raw;
        const unsigned short* b1 = (const unsigned short*)b1_raw;
        const unsigned short* b2 = (const unsigned short*)b2_raw;
        for (int i = t; i < 4 * CH; i += 256) sW1[i] = bf2f(W1[i]);
        if (t < CH) { sb1[t] = bf2f(b1[t]); sb2f[t] = bf2f(b2[t]); }
        const unsigned short* W2 = (const unsigned short*)W2_raw;
        for (int i = t; i < CH * CH; i += 256)      // coalesced
            sW2T[(i % CH) * HSTR + i / CH] = (_Float16)bf2f(W2[i]);
    }
    for (int i = t; i < CH * (HSTR - CH); i += 256)
        sW2T[(i / (HSTR - CH)) * HSTR + CH + (i % (HSTR - CH))] = (_Float16)0.0f;
    __syncthreads();

    if (blockIdx.x == 0 && t == 0) *magic = 0xCAFEBABEu;

    const int end = (int)offs[ncells];
    const int lane = t & 63;
    const int wid = t >> 6;
    const int m15 = lane & 15;
    const int quad = lane >> 4;
    const int totalWaves = gridDim.x * 4;
    const int nChunks = (end + 63) >> 6;

    int wv = blockIdx.x * 4 + wid;
    if (wv < nChunks) {
        uint4 prm[4];
        unsigned char hb;
        {
            hb = chHead[wv];
            const int cs0 = wv * 64;
#pragma unroll
            for (int mt = 0; mt < 4; ++mt) {
                int idx = cs0 + mt * 16 + m15;
                if (idx > end - 1) idx = end - 1;
                prm[mt] = precs[idx];
            }
        }

        for (;;) {
            const int chunkStart = wv * 64;
            const bool active = chunkStart + lane < end;
            const int wvn = wv + totalWaves;
            const bool hasNext = wvn < nChunks;

            // ---- decode records.
            int gm[4];
            float pmx[4], pmy[4], pmz[4], pmw[4];
#pragma unroll
            for (int mt = 0; mt < 4; ++mt) {
                gm[mt] = (int)prm[mt].z;
                const int cellin = gm[mt] & (HW_ - 1);
                const float cx = fmaf((float)(cellin & 127), 0.78125f, -49.609375f);
                const float cy = fmaf((float)(cellin >> 7), 0.78125f, -49.609375f);
                pmx[mt] = cx + h2f((unsigned short)(prm[mt].x & 0xFFFFu));
                pmy[mt] = cy + h2f((unsigned short)(prm[mt].x >> 16));
                pmz[mt] = h2f((unsigned short)(prm[mt].y & 0xFFFFu));
                pmw[mt] = h2f((unsigned short)(prm[mt].y >> 16));
            }
            const int g = active ? gm[quad] : -1;   // own record = gather mt=quad

            // ---- segment bookkeeping (R13-verified).
            const int gprev = __shfl_up(g, 1);
            const bool isHead = active && (lane == 0 || gprev != g);
            const unsigned long long headmask = __ballot(isHead);
            const int cellLocal = active
                ? (__popcll(headmask << (63 - lane)) - 1) : 255;
            const int ncellsW = __popcll(headmask);
            if (isHead) {
                unsigned int row = (unsigned int)g;
                if (cellLocal == 0 && !hb)
                    row = (unsigned int)(ncells + wv);
                sCellG[wid][cellLocal] = row;
            }

            // ---- prefetch next chunk (hidden under Af + nt pipeline).
            uint4 prmN[4];
            unsigned char hbN = 0;
            if (hasNext) {
                hbN = chHead[wvn];
                const int csn = wvn * 64;
#pragma unroll
                for (int mt = 0; mt < 4; ++mt) {
                    int idx = csn + mt * 16 + m15;
                    if (idx > end - 1) idx = end - 1;
                    prmN[mt] = precs[idx];
                }
            }

            // ---- layer 1 transposed: A-frag values born in registers.
            half8_t Af[3][4];
#pragma unroll
            for (int ks = 0; ks < 3; ++ks) {
                const int kb = ks * 32 + quad * 8;
                if (kb < 80) {
                    const float4 wa0 = *(const float4*)&sW1[0 * CH + kb];
                    const float4 wb0 = *(const float4*)&sW1[0 * CH + kb + 4];
                    const float4 wa1 = *(const float4*)&sW1[1 * CH + kb];
                    const float4 wb1 = *(const float4*)&sW1[1 * CH + kb + 4];
                    const float4 wa2 = *(const float4*)&sW1[2 * CH + kb];
                    const float4 wb2 = *(const float4*)&sW1[2 * CH + kb + 4];
                    const float4 wa3 = *(const float4*)&sW1[3 * CH + kb];
                    const float4 wb3 = *(const float4*)&sW1[3 * CH + kb + 4];
                    const float4 ba  = *(const float4*)&sb1[kb];
                    const float4 bb  = *(const float4*)&sb1[kb + 4];
                    float w0[8] = {wa0.x, wa0.y, wa0.z, wa0.w, wb0.x, wb0.y, wb0.z, wb0.w};
                    float w1[8] = {wa1.x, wa1.y, wa1.z, wa1.w, wb1.x, wb1.y, wb1.z, wb1.w};
                    float w2[8] = {wa2.x, wa2.y, wa2.z, wa2.w, wb2.x, wb2.y, wb2.z, wb2.w};
                    float w3[8] = {wa3.x, wa3.y, wa3.z, wa3.w, wb3.x, wb3.y, wb3.z, wb3.w};
                    float bv[8] = {ba.x, ba.y, ba.z, ba.w, bb.x, bb.y, bb.z, bb.w};
#pragma unroll
                    for (int mt = 0; mt < 4; ++mt) {
                        half8_t v;
#pragma unroll
                        for (int j = 0; j < 8; ++j) {
                            float hv = bv[j];
                            hv = fmaf(pmx[mt], w0[j], hv);
                            hv = fmaf(pmy[mt], w1[j], hv);
                            hv = fmaf(pmz[mt], w2[j], hv);
                            hv = fmaf(pmw[mt], w3[j], hv);
                            v[j] = (_Float16)fmaxf(hv, 0.0f);
                        }
                        Af[ks][mt] = v;
                    }
                } else {
                    const half8_t z8 = {0, 0, 0, 0, 0, 0, 0, 0};
#pragma unroll
                    for (int mt = 0; mt < 4; ++mt) Af[ks][mt] = z8;
                }
            }

            // ---- selector columns for MFMA2.
            int cl[2][8];
#pragma unroll
            for (int ks2 = 0; ks2 < 2; ++ks2)
#pragma unroll
                for (int j = 0; j < 8; ++j)
                    cl[ks2][j] = __shfl(cellLocal, ks2 * 32 + quad * 8 + j);

            const int nMt2 = (ncellsW + 15) >> 4;
            _Float16* embT = &sEmb[wid][0];

            auto mfma1_epi = [&](int nt, int slice) {
                f32x4_t acc[4];
#pragma unroll
                for (int mt = 0; mt < 4; ++mt) acc[mt] = (f32x4_t){0.0f, 0.0f, 0.0f, 0.0f};
#pragma unroll
                for (int ks = 0; ks < 3; ++ks) {
                    const half8_t Bf = *(const half8_t*)
                        &sW2T[(nt * 16 + m15) * HSTR + ks * 32 + quad * 8];
#pragma unroll
                    for (int mt = 0; mt < 4; ++mt)
                        acc[mt] = __builtin_amdgcn_mfma_f32_16x16x32_f16(
                            Af[ks][mt], Bf, acc[mt], 0, 0, 0);
                }
                const float bb2 = sb2f[nt * 16 + m15];
#pragma unroll
                for (int mt = 0; mt < 4; ++mt) {
                    const f32x4_t a = acc[mt];
                    half4_t v;
                    v[0] = (_Float16)fmaxf(a[0] + bb2, 0.0f);
                    v[1] = (_Float16)fmaxf(a[1] + bb2, 0.0f);
                    v[2] = (_Float16)fmaxf(a[2] + bb2, 0.0f);
                    v[3] = (_Float16)fmaxf(a[3] + bb2, 0.0f);
                    *(half4_t*)&embT[slice * ESLICE + m15 * ESTR + mt * 16 + quad * 4] = v;
                }
            };

            if (nMt2 == 1) {
                // ======== fast path (<=16 cells): pipelined ========
                half8_t A2h[2];
#pragma unroll
                for (int ks2 = 0; ks2 < 2; ++ks2)
#pragma unroll
                    for (int j = 0; j < 8; ++j)
                        A2h[ks2][j] = (cl[ks2][j] == m15) ? (_Float16)1 : (_Float16)0;
                unsigned int rowr[4];
#pragma unroll
                for (int r = 0; r < 4; ++r) {
                    const int cell = quad * 4 + r;
                    rowr[r] = (cell < ncellsW) ? sCellG[wid][cell] : 0xFFFFFFFFu;
                }

                auto mfma2_store = [&](int nt, int slice) {
                    half8_t B2[2];
#pragma unroll
                    for (int ks2 = 0; ks2 < 2; ++ks2)
                        B2[ks2] = *(const half8_t*)
                            &embT[slice * ESLICE + m15 * ESTR + ks2 * 32 + quad * 8];
                    f32x4_t acc2 = (f32x4_t){0.0f, 0.0f, 0.0f, 0.0f};
#pragma unroll
                    for (int ks2 = 0; ks2 < 2; ++ks2)
                        acc2 = __builtin_amdgcn_mfma_f32_16x16x32_f16(
                            A2h[ks2], B2[ks2], acc2, 0, 0, 0);
                    float* const plane = sums + (size_t)nt * (size_t)P;
#pragma unroll
                    for (int r = 0; r < 4; ++r)
                        if (rowr[r] != 0xFFFFFFFFu)
                            plane[((size_t)rowr[r] << 4) + m15] = acc2[r];
                };

                mfma1_epi(0, 0);
                mfma1_epi(1, 1);
                mfma2_store(0, 0);
                mfma1_epi(2, 0);
                mfma2_store(1, 1);
                mfma1_epi(3, 1);
                mfma2_store(2, 0);
                mfma1_epi(4, 0);
                mfma2_store(3, 1);
                mfma2_store(4, 0);
            } else {
                // ======== general path (>16 cells in chunk) ========
#pragma unroll 1
                for (int nt = 0; nt < 5; ++nt) {
                    mfma1_epi(nt, 0);
                    half8_t B2[2];
#pragma unroll
                    for (int ks2 = 0; ks2 < 2; ++ks2)
                        B2[ks2] = *(const half8_t*)
                            &embT[m15 * ESTR + ks2 * 32 + quad * 8];
                    float* const plane = sums + (size_t)nt * (size_t)P;
                    for (int mt2 = 0; mt2 < nMt2; ++mt2) {
                        const int m2 = mt2 * 16 + m15;
                        f32x4_t acc2 = (f32x4_t){0.0f, 0.0f, 0.0f, 0.0f};
#pragma unroll
                        for (int ks2 = 0; ks2 < 2; ++ks2) {
                            half8_t A2;
#pragma unroll
                            for (int j = 0; j < 8; ++j)
                                A2[j] = (cl[ks2][j] == m2) ? (_Float16)1 : (_Float16)0;
                            acc2 = __builtin_amdgcn_mfma_f32_16x16x32_f16(
                                A2, B2[ks2], acc2, 0, 0, 0);
                        }
#pragma unroll
                        for (int r = 0; r < 4; ++r) {
                            const int cell = mt2 * 16 + quad * 4 + r;
                            if (cell < ncellsW) {
                                const unsigned int row = sCellG[wid][cell];
                                plane[((size_t)row << 4) + m15] = acc2[r];
                            }
                        }
                    }
                }
            }

            if (!hasNext) break;
            wv = wvn; hb = hbN;
#pragma unroll
            for (int mt = 0; mt < 4; ++mt) prm[mt] = prmN[mt];
        }
    }
}

// ---------------------------------------------------------------------------
// Head: half-row blocks — 1024 blocks x 64 cells. LDS 14KB; Wp A-frags
// direct from global (hi/lo f16, L2-hot). Per-block Wp-dtype probe (R28).
// Block 0 runs the diagnostics beacon.
// ---------------------------------------------------------------------------
__global__ __launch_bounds__(256, 2) void k_head(
    const float* __restrict__ sums,
    const unsigned int* __restrict__ cnt,
    const unsigned int* __restrict__ offs,
    const void* __restrict__ Wp_raw,
    const void* __restrict__ bp_raw,
    const void* __restrict__ gamma_raw,
    const void* __restrict__ beta_raw,
    const void* __restrict__ rmean_raw,
    const void* __restrict__ rvar_raw,
    const unsigned int* __restrict__ magic,
    float* __restrict__ out,
    int b0, int ncells, int P, int hostbits)
{
    __shared__ _Float16 sMean[64 * MSTR];      // [cell64][k], k 80..103 zero
    __shared__ float sAlpha[COUT_], sDelta[COUT_];
    __shared__ float sRedF[4];
    __shared__ unsigned int sRedU[4];
    __shared__ int sWf32;

    const int t = threadIdx.x;
    probe_f32((const unsigned short*)Wp_raw, 512, t, &sWf32);
    __syncthreads();
    const int wf32 = sWf32;

    const int blk = blockIdx.x;
    const int bl = blk >> 8;
    const int rem = blk & 255;
    const int hrow = rem >> 1, half = rem & 1;
    const int bg = b0 + bl;
    const int lane = t & 63;
    const int wid = t >> 6;
    const int m15 = lane & 15;
    const int quad = lane >> 4;

    if (t < COUT_) {
        if (wf32) {
            const float rs = rsqrtf(((const float*)rvar_raw)[t] + 1e-5f);
            const float al = ((const float*)gamma_raw)[t] * rs;
            sAlpha[t] = al;
            sDelta[t] = al * (((const float*)bp_raw)[t] - ((const float*)rmean_raw)[t])
                        + ((const float*)beta_raw)[t];
        } else {
            const float rs = rsqrtf(bf2f(((const unsigned short*)rvar_raw)[t]) + 1e-5f);
            const float al = bf2f(((const unsigned short*)gamma_raw)[t]) * rs;
            sAlpha[t] = al;
            sDelta[t] = al * (bf2f(((const unsigned short*)bp_raw)[t])
                              - bf2f(((const unsigned short*)rmean_raw)[t]))
                        + bf2f(((const unsigned short*)beta_raw)[t]);
        }
    }

    // ---- A-fragments direct from global (fragment layout, L2-hot), hi/lo.
    half8_t Ahi[2][3], Alo[2][3];
#pragma unroll
    for (int m = 0; m < 2; ++m) {
        const int d = (wid * 2 + m) * 16 + m15;
#pragma unroll
        for (int ks = 0; ks < 3; ++ks) {
#pragma unroll
            for (int j = 0; j < 8; ++j) {
                const int k = ks * 32 + quad * 8 + j;
                float w = 0.0f;
                if (k < CH)
                    w = wf32 ? ((const float*)Wp_raw)[k * COUT_ + d]
                             : bf2f(((const unsigned short*)Wp_raw)[k * COUT_ + d]);
                const _Float16 hi = (_Float16)w;
                Ahi[m][ks][j] = hi;
                Alo[m][ks][j] = (_Float16)(w - (float)hi);
            }
        }
    }

    // ---- stage mean[cell64][k] f16 (+zero pad k 80..103).
    const int cellbase = bl * HW_ + hrow * BEVW + half * 64;
    for (int i = t; i < 64 * 26; i += 256) {
        const int w = i / 26, c4 = i % 26;
        _Float16* m = &sMean[w * MSTR + c4 * 4];
        if (c4 < 20) {
            const int nt = c4 >> 2, q = c4 & 3;
            const int cell = cellbase + w;
            const unsigned int c = cnt[cell];
            float4 s = {0.0f, 0.0f, 0.0f, 0.0f};
            if (c > 0) {
                const float4* plane4 = (const float4*)(sums + (size_t)nt * (size_t)P);
                s = plane4[cell * 4 + q];
                const unsigned int o = offs[cell];
                const int bA = (int)(o >> 6) + 1;
                const int bB = (int)((o + c - 1) >> 6);
                for (int b = bA; b <= bB; ++b) {
                    const float4 st = plane4[(ncells + b) * 4 + q];
                    s.x += st.x; s.y += st.y; s.z += st.z; s.w += st.w;
                }
            }
            const float inv = 1.0f / fmaxf((float)c, 1.0f);
            m[0] = (_Float16)(s.x * inv);
            m[1] = (_Float16)(s.y * inv);
            m[2] = (_Float16)(s.z * inv);
            m[3] = (_Float16)(s.w * inv);
        } else {
            m[0] = (_Float16)0.0f; m[1] = (_Float16)0.0f;
            m[2] = (_Float16)0.0f; m[3] = (_Float16)0.0f;
        }
    }
    __syncthreads();

    float alph[2][4], delt[2][4];
#pragma unroll
    for (int m = 0; m < 2; ++m)
#pragma unroll
        for (int r = 0; r < 4; ++r) {
            const int d = (wid * 2 + m) * 16 + quad * 4 + r;
            alph[m][r] = sAlpha[d];
            delt[m][r] = sDelta[d];
        }

#pragma unroll
    for (int n = 0; n < 4; ++n) {
        half8_t Bf[3];
#pragma unroll
        for (int ks = 0; ks < 3; ++ks)
            Bf[ks] = *(const half8_t*)&sMean[(n * 16 + m15) * MSTR + ks * 32 + quad * 8];
#pragma unroll
        for (int m = 0; m < 2; ++m) {
            f32x4_t acc = (f32x4_t){0.0f, 0.0f, 0.0f, 0.0f};
#pragma unroll
            for (int ks = 0; ks < 3; ++ks) {
                acc = __builtin_amdgcn_mfma_f32_16x16x32_f16(Ahi[m][ks], Bf[ks], acc, 0, 0, 0);
                acc = __builtin_amdgcn_mfma_f32_16x16x32_f16(Alo[m][ks], Bf[ks], acc, 0, 0, 0);
            }
#pragma unroll
            for (int r = 0; r < 4; ++r) {
                const int d = (wid * 2 + m) * 16 + quad * 4 + r;
                float o = fmaxf(fmaf(acc[r], alph[m][r], delt[m][r]), 0.0f);
                o = fminf(o, 512.0f);
                out[(((size_t)bg * COUT_ + d) * BEVH + hrow) * BEVW
                    + half * 64 + n * 16 + m15] = o;
            }
        }
    }

    // ---- diagnostics beacon (block 0 only; healthy run writes nothing).
    if (blk == 0) {
        unsigned int cs = 0;
        for (int i = t; i < HW_; i += 256) cs += cnt[i];
        float sl = 0.0f;
        for (int i = t; i < CH * CH; i += 256) sl += fabsf(sums[i]);
#pragma unroll
        for (int off = 32; off > 0; off >>= 1) {
            cs += __shfl_down(cs, off);
            sl += __shfl_down(sl, off);
        }
        if (lane == 0) { sRedU[wid] = cs; sRedF[wid] = sl; }
        __syncthreads();
        if (t == 0) {
            const unsigned int csum = sRedU[0] + sRedU[1] + sRedU[2] + sRedU[3];
            const float ssum = sRedF[0] + sRedF[1] + sRedF[2] + sRedF[3];
            int code = hostbits;
            if (*magic != 0xCAFEBABEu) code |= 1;
            if (csum < 1000u)          code |= 2;
            if (!(ssum > 0.0f))        code |= 4;
            if (code) {
                code |= (wf32 ? 32 : 0);
                out[0] = 1024.0f * (float)code;
            }
        }
    }
}

extern "C" void kernel_launch(void* const* d_in, const int* in_sizes, int n_in,
                              void* d_out, int out_size, void* d_ws, size_t ws_size,
                              hipStream_t stream) {
    const void* pts   = d_in[0];
    const void* W1    = d_in[1];
    const void* b1    = d_in[2];
    const void* W2    = d_in[3];
    const void* b2    = d_in[4];
    const void* Wp    = d_in[5];
    const void* bp    = d_in[6];
    const void* gamma = d_in[7];
    const void* beta  = d_in[8];
    const void* rmean = d_in[9];
    const void* rvar  = d_in[10];

    int hostbits = 0;
    if (n_in != 11 ||
        in_sizes[0] != B_ * NP_ * 4 ||
        in_sizes[1] != 4 * CH  || in_sizes[2] != CH ||
        in_sizes[3] != CH * CH || in_sizes[4] != CH ||
        in_sizes[5] != CH * COUT_ || in_sizes[6] != COUT_ ||
        out_size != B_ * COUT_ * HW_)
        hostbits |= 8;
    if (ws_size < SCRATCH_OFF + PER_BATCH + EXTRA_BYTES) hostbits |= 16;

    unsigned int* magic = (unsigned int*)((char*)d_ws + MAGIC_OFF);
    char* base = (char*)d_ws + SCRATCH_OFF;
    const size_t avail = (ws_size > SCRATCH_OFF + EXTRA_BYTES)
                       ? (ws_size - SCRATCH_OFF - EXTRA_BYTES) : PER_BATCH;
    int nb = (int)(avail / PER_BATCH);
    if (nb < 1) nb = 1;
    if (nb > B_) nb = B_;

    // Layout: cnt | sums (5 planes, incl. staging rows) | offs(+4) |
    //         chHead | rank | prec (16B-aligned)
    unsigned int*   cnt      = (unsigned int*)base;
    float*          sums     = (float*)(cnt + (size_t)nb * HW_);
    const size_t    sumsFl   = (size_t)5 * ((size_t)nb * HW_ + (size_t)nb * NCHK) * 16;
    unsigned int*   offs     = (unsigned int*)(sums + sumsFl);
    unsigned char*  chHead   = (unsigned char*)(offs + (size_t)nb * HW_ + 4);
    unsigned int*   rank     = (unsigned int*)((char*)chHead
                               + (((size_t)nb * NCHK + 3) & ~(size_t)3));
    char*           palign   = (char*)(rank + (size_t)nb * NP_);
    palign = (char*)(((size_t)palign + 15) & ~(size_t)15);
    uint4*          prec     = (uint4*)palign;

    for (int b0 = 0; b0 < B_; b0 += nb) {
        const int bcnt = (B_ - b0 < nb) ? (B_ - b0) : nb;
        const int ncells = bcnt * HW_;
        const int npts   = bcnt * NP_;
        const int nblk   = ncells >> 10;      // 1024 cells per scan block
        const int P      = (ncells + bcnt * NCHK) * 16;   // plane stride (f32)

        // Zero cnt + diag window (contiguous: cnt then sums prefix) via
        // memset node -- replaces the k_init dispatch (R28).
        hipMemsetAsync(cnt, 0, (size_t)ncells * 4 + 25600, stream);

        k_bin<<<(npts / 2 + 255) / 256, 256, 0, stream>>>(
            pts, cnt, rank, b0, npts);

        k_scan<<<nblk, 256, 0, stream>>>(cnt, offs, chHead, nblk, ncells);

        k_scatteridx<<<(npts / 4 + 255) / 256, 256, 0, stream>>>(
            pts, offs, rank, prec, b0, npts);

        k_mlp_mfma<<<768, 256, 0, stream>>>(
            prec, W1, b1, W2, b2, magic, offs, chHead,
            sums, ncells, P);

        k_head<<<bcnt * BEVH * 2, 256, 0, stream>>>(
            sums, cnt, offs, Wp, bp, gamma, beta, rmean, rvar, magic,
            (float*)d_out, b0, ncells, P, hostbits);
    }
}

// Round 16
// 206.516 us; speedup vs baseline: 1.0287x; 1.0287x over previous
//
#include <hip/hip_runtime.h>
#include <hip/hip_bf16.h>

// PointsToBEV round 29 (final): revert to R27, the double-confirmed best
// (206.74/206.77us). R28's k_init-deletion regressed +5.7us: hipMemsetAsync
// is itself a fill-kernel dispatch (no boundary saved) and the per-block
// dtype probes added a serial 512-short+barrier preamble to ~4100 blocks.
// Session ledger 284->206.7us: spill fix (-30, launch_bounds 256,2), MFMA
// head (-14), 16B records+2-slice pipeline (-3), rank-based atomic-free
// scatter (-28). Nulls: XCD scatter, NT loads, grid retunes, launch fusion.
// Structure is a 5-phase serial dependency chain (bin->scan->scatter->mlp->
// head), each phase latency-bound on irregular access, none HW-roofline.

#define B_    4
#define NP_   200000
#define CH    80
#define COUT_ 128
#define BEVH  128
#define BEVW  128
#define HW_   (BEVH * BEVW)
#define NCHK  (NP_ / 64)        // 3125 chunks per batch (NP_ % 64 == 0)

// Per-batch bytes: cnt(HW u32) + sums+staging((HW+NCHK)*80 f32) +
// offs(HW u32 +pad) + chHead(NCHK u8) + rank(NP u32) + prec(NP*16)
#define PER_BATCH ((size_t)HW_ * 328 + (size_t)NCHK * 321 + (size_t)NP_ * 20)
#define EXTRA_BYTES 512

#define MAGIC_OFF   128
#define SCRATCH_OFF 256

typedef _Float16 half4_t __attribute__((ext_vector_type(4)));
typedef _Float16 half8_t __attribute__((ext_vector_type(8)));
typedef float    f32x4_t __attribute__((ext_vector_type(4)));
typedef unsigned short ushort8_t __attribute__((ext_vector_type(8)));

#define HSTR 104   // W2T k-stride in f16 (52 dwords -> 2-way banks, free)
#define ESTR 72    // embT pt-stride in f16 (36 dwords -> 2-way banks, free)
#define ESLICE (16 * ESTR)
#define MSTR 104   // sMean k-stride in f16 (16B-aligned, 2-way free)

__device__ __forceinline__ float bf2f(unsigned short u) {
    return __uint_as_float(((unsigned int)u) << 16);
}
__device__ __forceinline__ unsigned short f2h(float f) {
    return __builtin_bit_cast(unsigned short, (_Float16)f);
}
__device__ __forceinline__ float h2f(unsigned short u) {
    return (float)__builtin_bit_cast(_Float16, u);
}

__device__ __forceinline__ int cell_of(float px, float py, int bloc) {
    const int ix = (int)floorf((px + 50.0f) / 0.78125f);
    const int iy = (int)floorf((py + 50.0f) / 0.78125f);
    if (ix < 0 || ix >= BEVW || iy < 0 || iy >= BEVH) return -1;
    return bloc * HW_ + iy * BEVW + ix;
}

// Load 2 consecutive points (p0 even) as one vector op where possible.
__device__ __forceinline__ void load_pt2(const void* pts_raw, size_t pbase,
                                         int pf32, float x[2], float y[2],
                                         float z[2], float w[2]) {
    if (pf32) {
        const float4 a = ((const float4*)pts_raw)[pbase];
        const float4 b = ((const float4*)pts_raw)[pbase + 1];
        x[0] = a.x; y[0] = a.y; z[0] = a.z; w[0] = a.w;
        x[1] = b.x; y[1] = b.y; z[1] = b.z; w[1] = b.w;
    } else {
        const ushort8_t u = ((const ushort8_t*)pts_raw)[pbase >> 1];
        x[0] = bf2f(u[0]); y[0] = bf2f(u[1]); z[0] = bf2f(u[2]); w[0] = bf2f(u[3]);
        x[1] = bf2f(u[4]); y[1] = bf2f(u[5]); z[1] = bf2f(u[6]); w[1] = bf2f(u[7]);
    }
}

// ---------------------------------------------------------------------------
// k_init: grid-stride zero of cnt + diag window; blocks 0/1 run the dtype
// probes. flags[0]=params fp32, flags[1]=points fp32.
// ---------------------------------------------------------------------------
__global__ __launch_bounds__(256) void k_init(
    float4* __restrict__ zp, int n4,
    const unsigned short* __restrict__ w1bits,
    const unsigned short* __restrict__ ptsbits,
    unsigned int* __restrict__ flags)
{
    const int t = threadIdx.x;
    if (blockIdx.x < 2 && t < 64) {
        const int which = blockIdx.x;
        const unsigned short* src = which ? ptsbits : w1bits;
        const int n = which ? 512 : 320;
        float m = 0.0f;
        for (int i = t; i < n; i += 64) {
            const float a = fabsf(bf2f(src[i]));
            if (a == a) m = fmaxf(m, a);
        }
#pragma unroll
        for (int off = 32; off > 0; off >>= 1)
            m = fmaxf(m, __shfl_down(m, off));
        if (t == 0) flags[which] = (m > 1.0e6f) ? 1u : 0u;
    }
    const float4 z = {0.0f, 0.0f, 0.0f, 0.0f};
    for (int i = blockIdx.x * 256 + t; i < n4; i += gridDim.x * 256)
        zp[i] = z;
}

// ---------------------------------------------------------------------------
// Phase A: histogram (2 points per thread). atomicAdd's return value is the
// point's within-cell rank -- persisted (coalesced) for the atomic-free
// scatter.
// ---------------------------------------------------------------------------
__global__ __launch_bounds__(256) void k_bin(
    const void* __restrict__ pts_raw,
    const unsigned int* __restrict__ flags,
    unsigned int* __restrict__ cnt,
    unsigned int* __restrict__ rank,
    int b0, int npts)
{
    const int gid = blockIdx.x * 256 + threadIdx.x;
    const int p0 = gid * 2;
    if (p0 >= npts) return;
    const int bloc = p0 / NP_;                 // p0 even, NP_ even: pair same batch
    float x[2], y[2], z[2], w[2];
    load_pt2(pts_raw, (size_t)b0 * NP_ + p0, (int)flags[1], x, y, z, w);
#pragma unroll
    for (int k = 0; k < 2; ++k) {
        const int g = cell_of(x[k], y[k], bloc);
        if (g >= 0) rank[p0 + k] = atomicAdd(&cnt[g], 1u);
    }
}

// ---------------------------------------------------------------------------
// Phase B (fused scan): per-block redundant base re-sum (L2-hot, no
// cross-block sync), local scan, offs (+sentinel). chHead fully written
// here: each nonempty cell sets 1 at its start if chunk-aligned, and 0 for
// every chunk boundary strictly inside its span. Spans partition [0, end)
// -> exactly-once coverage, race-free.
// ---------------------------------------------------------------------------
__global__ __launch_bounds__(256) void k_scan(
    const unsigned int* __restrict__ cnt,
    unsigned int* __restrict__ offs,
    unsigned char* __restrict__ chHead,
    int nblocks, int n)
{
    __shared__ unsigned int sd[256];
    __shared__ unsigned int sBase;
    const int t = threadIdx.x;
    const int blk = blockIdx.x;
    const int i0 = blk * 1024 + t * 4;
    const unsigned int c0 = cnt[i0], c1 = cnt[i0 + 1],
                       c2 = cnt[i0 + 2], c3 = cnt[i0 + 3];
    const unsigned int s4 = c0 + c1 + c2 + c3;

    unsigned int bsum = 0;
    const int q4 = blk << 8;
    const uint4* cnt4 = (const uint4*)cnt;
    for (int i = t; i < q4; i += 256) {
        const uint4 v = cnt4[i];
        bsum += v.x + v.y + v.z + v.w;
    }
    sd[t] = bsum;
    __syncthreads();
    for (int d = 128; d > 0; d >>= 1) {
        if (t < d) sd[t] += sd[t + d];
        __syncthreads();
    }
    if (t == 0) sBase = sd[0];
    __syncthreads();

    sd[t] = s4;
    __syncthreads();
    for (int d = 1; d < 256; d <<= 1) {
        const unsigned int add = (t >= d) ? sd[t - d] : 0u;
        __syncthreads();
        sd[t] += add;
        __syncthreads();
    }
    unsigned int run = sBase + sd[t] - s4;    // exclusive prefix
    const unsigned int cs[4] = {c0, c1, c2, c3};
#pragma unroll
    for (int j = 0; j < 4; ++j) {
        offs[i0 + j] = run;
        const unsigned int c = cs[j];
        if (c) {
            if (!(run & 63u)) chHead[run >> 6] = 1;
            const unsigned int bA = (run >> 6) + 1;
            const unsigned int bB = (run + c - 1) >> 6;
            for (unsigned int b = bA; b <= bB; ++b) chHead[b] = 0;
        }
        run += c;
    }
    if (blk == nblocks - 1 && t == 255) offs[n] = run;
}

// ---------------------------------------------------------------------------
// Phase C: atomic-free scatter, 4 points/thread. pos = offs[g] + rank[p];
// all chains independent (coalesced point+rank loads, one L2-hot random
// offs read, one random 16B store). rec = {dx|dy, z|w (fp16), g, 0}.
// ---------------------------------------------------------------------------
__global__ __launch_bounds__(256) void k_scatteridx(
    const void* __restrict__ pts_raw,
    const unsigned int* __restrict__ flags,
    const unsigned int* __restrict__ offs,
    const unsigned int* __restrict__ rank,
    uint4* __restrict__ prec,
    int b0, int npts)
{
    const int gid = blockIdx.x * 256 + threadIdx.x;
    const int p0 = gid * 4;
    if (p0 >= npts) return;
    const int bloc = p0 / NP_;                 // NP_ % 4 == 0: quad same batch
    float x[4], y[4], z[4], w[4];
    load_pt2(pts_raw, (size_t)b0 * NP_ + p0, (int)flags[1], x, y, z, w);
    load_pt2(pts_raw, (size_t)b0 * NP_ + p0 + 2, (int)flags[1], x + 2, y + 2,
             z + 2, w + 2);
    const uint4 rk = *(const uint4*)&rank[p0];
    const unsigned int rks[4] = {rk.x, rk.y, rk.z, rk.w};

    int g4[4];
#pragma unroll
    for (int k = 0; k < 4; ++k)
        g4[k] = cell_of(x[k], y[k], bloc);

#pragma unroll
    for (int k = 0; k < 4; ++k) {
        const int g = g4[k];
        if (g < 0) continue;
        const unsigned int pos = offs[g] + rks[k];
        const int cellin = g & (HW_ - 1);
        const float cx = fmaf((float)(cellin & 127), 0.78125f, -49.609375f);
        const float cy = fmaf((float)(cellin >> 7), 0.78125f, -49.609375f);
        uint4 r;
        r.x = (unsigned int)f2h(x[k] - cx) | ((unsigned int)f2h(y[k] - cy) << 16);
        r.y = (unsigned int)f2h(z[k]) | ((unsigned int)f2h(w[k]) << 16);
        r.z = (unsigned int)g;
        r.w = 0u;
        prec[pos] = r;
    }
}

// ---------------------------------------------------------------------------
// Phase D (persistent MFMA): waves grid-stride over 64-point chunks.
// 16B records: 4 gather loads/lane, own-g = gm[quad]. Next-chunk prefetch.
// Fast path: 2-slice embT pipeline hides the per-nt LDS round-trip.
// ---------------------------------------------------------------------------
__global__ __launch_bounds__(256, 2) void k_mlp_mfma(
    const uint4* __restrict__ precs,
    const void* __restrict__ W1_raw,
    const void* __restrict__ b1_raw,
    const void* __restrict__ W2_raw,
    const void* __restrict__ b2_raw,
    const unsigned int* __restrict__ flags,
    unsigned int* __restrict__ magic,
    const unsigned int* __restrict__ offs,    // ncells+1 (sentinel = total)
    const unsigned char* __restrict__ chHead,
    float* __restrict__ sums,                 // 5 planes of P floats
    int ncells, int P)
{
    __shared__ float sW1[4 * CH];             // [f][k]
    __shared__ float sb1[CH];
    __shared__ float sb2f[CH];
    __shared__ _Float16 sW2T[80 * HSTR];      // [ch_out][k], k 80..103 zero
    __shared__ _Float16 sEmb[4][2 * ESLICE];  // per-wave 2-slice embT dbuf
    __shared__ unsigned int sCellG[4][64];

    const int t = threadIdx.x;
    const int wf32 = (int)flags[0];

    // ---- staging (W2 read coalesced, LDS-scatter write).
    if (wf32) {
        const float* W1 = (const float*)W1_raw;
        const float* b1 = (const float*)b1_raw;
        const float* b2 = (const float*)b2_raw;
        for (int i = t; i < 4 * CH; i += 256) sW1[i] = W1[i];
        if (t < CH) { sb1[t] = b1[t]; sb2f[t] = b2[t]; }
        const float* W2 = (const float*)W2_raw;
        for (int i = t; i < CH * CH; i += 256)      // i = c*80 + d, coalesced
            sW2T[(i % CH) * HSTR + i / CH] = (_Float16)W2[i];
    } else {
        const unsigned short* W1 = (const unsigned short*)W1_raw;
        const unsigned short* b1 = (const unsigned short*)b1_raw;
        const unsigned short* b2 = (const unsigned short*)b2_raw;
        for (int i = t; i < 4 * CH; i += 256) sW1[i] = bf2f(W1[i]);
        if (t < CH) { sb1[t] = bf2f(b1[t]); sb2f[t] = bf2f(b2[t]); }
        const unsigned short* W2 = (const unsigned short*)W2_raw;
        for (int i = t; i < CH * CH; i += 256)      // coalesced
            sW2T[(i % CH) * HSTR + i / CH] = (_Float16)bf2f(W2[i]);
    }
    for (int i = t; i < CH * (HSTR - CH); i += 256)
        sW2T[(i / (HSTR - CH)) * HSTR + CH + (i % (HSTR - CH))] = (_Float16)0.0f;
    __syncthreads();

    if (blockIdx.x == 0 && t == 0) *magic = 0xCAFEBABEu;

    const int end = (int)offs[ncells];
    const int lane = t & 63;
    const int wid = t >> 6;
    const int m15 = lane & 15;
    const int quad = lane >> 4;
    const int totalWaves = gridDim.x * 4;
    const int nChunks = (end + 63) >> 6;

    int wv = blockIdx.x * 4 + wid;
    if (wv < nChunks) {
        uint4 prm[4];
        unsigned char hb;
        {
            hb = chHead[wv];
            const int cs0 = wv * 64;
#pragma unroll
            for (int mt = 0; mt < 4; ++mt) {
                int idx = cs0 + mt * 16 + m15;
                if (idx > end - 1) idx = end - 1;
                prm[mt] = precs[idx];
            }
        }

        for (;;) {
            const int chunkStart = wv * 64;
            const bool active = chunkStart + lane < end;
            const int wvn = wv + totalWaves;
            const bool hasNext = wvn < nChunks;

            // ---- decode records.
            int gm[4];
            float pmx[4], pmy[4], pmz[4], pmw[4];
#pragma unroll
            for (int mt = 0; mt < 4; ++mt) {
                gm[mt] = (int)prm[mt].z;
                const int cellin = gm[mt] & (HW_ - 1);
                const float cx = fmaf((float)(cellin & 127), 0.78125f, -49.609375f);
                const float cy = fmaf((float)(cellin >> 7), 0.78125f, -49.609375f);
                pmx[mt] = cx + h2f((unsigned short)(prm[mt].x & 0xFFFFu));
                pmy[mt] = cy + h2f((unsigned short)(prm[mt].x >> 16));
                pmz[mt] = h2f((unsigned short)(prm[mt].y & 0xFFFFu));
                pmw[mt] = h2f((unsigned short)(prm[mt].y >> 16));
            }
            const int g = active ? gm[quad] : -1;   // own record = gather mt=quad

            // ---- segment bookkeeping (R13-verified).
            const int gprev = __shfl_up(g, 1);
            const bool isHead = active && (lane == 0 || gprev != g);
            const unsigned long long headmask = __ballot(isHead);
            const int cellLocal = active
                ? (__popcll(headmask << (63 - lane)) - 1) : 255;
            const int ncellsW = __popcll(headmask);
            if (isHead) {
                unsigned int row = (unsigned int)g;
                if (cellLocal == 0 && !hb)
                    row = (unsigned int)(ncells + wv);
                sCellG[wid][cellLocal] = row;
            }

            // ---- prefetch next chunk (hidden under Af + nt pipeline).
            uint4 prmN[4];
            unsigned char hbN = 0;
            if (hasNext) {
                hbN = chHead[wvn];
                const int csn = wvn * 64;
#pragma unroll
                for (int mt = 0; mt < 4; ++mt) {
                    int idx = csn + mt * 16 + m15;
                    if (idx > end - 1) idx = end - 1;
                    prmN[mt] = precs[idx];
                }
            }

            // ---- layer 1 transposed: A-frag values born in registers.
            half8_t Af[3][4];
#pragma unroll
            for (int ks = 0; ks < 3; ++ks) {
                const int kb = ks * 32 + quad * 8;
                if (kb < 80) {
                    const float4 wa0 = *(const float4*)&sW1[0 * CH + kb];
                    const float4 wb0 = *(const float4*)&sW1[0 * CH + kb + 4];
                    const float4 wa1 = *(const float4*)&sW1[1 * CH + kb];
                    const float4 wb1 = *(const float4*)&sW1[1 * CH + kb + 4];
                    const float4 wa2 = *(const float4*)&sW1[2 * CH + kb];
                    const float4 wb2 = *(const float4*)&sW1[2 * CH + kb + 4];
                    const float4 wa3 = *(const float4*)&sW1[3 * CH + kb];
                    const float4 wb3 = *(const float4*)&sW1[3 * CH + kb + 4];
                    const float4 ba  = *(const float4*)&sb1[kb];
                    const float4 bb  = *(const float4*)&sb1[kb + 4];
                    float w0[8] = {wa0.x, wa0.y, wa0.z, wa0.w, wb0.x, wb0.y, wb0.z, wb0.w};
                    float w1[8] = {wa1.x, wa1.y, wa1.z, wa1.w, wb1.x, wb1.y, wb1.z, wb1.w};
                    float w2[8] = {wa2.x, wa2.y, wa2.z, wa2.w, wb2.x, wb2.y, wb2.z, wb2.w};
                    float w3[8] = {wa3.x, wa3.y, wa3.z, wa3.w, wb3.x, wb3.y, wb3.z, wb3.w};
                    float bv[8] = {ba.x, ba.y, ba.z, ba.w, bb.x, bb.y, bb.z, bb.w};
#pragma unroll
                    for (int mt = 0; mt < 4; ++mt) {
                        half8_t v;
#pragma unroll
                        for (int j = 0; j < 8; ++j) {
                            float hv = bv[j];
                            hv = fmaf(pmx[mt], w0[j], hv);
                            hv = fmaf(pmy[mt], w1[j], hv);
                            hv = fmaf(pmz[mt], w2[j], hv);
                            hv = fmaf(pmw[mt], w3[j], hv);
                            v[j] = (_Float16)fmaxf(hv, 0.0f);
                        }
                        Af[ks][mt] = v;
                    }
                } else {
                    const half8_t z8 = {0, 0, 0, 0, 0, 0, 0, 0};
#pragma unroll
                    for (int mt = 0; mt < 4; ++mt) Af[ks][mt] = z8;
                }
            }

            // ---- selector columns for MFMA2.
            int cl[2][8];
#pragma unroll
            for (int ks2 = 0; ks2 < 2; ++ks2)
#pragma unroll
                for (int j = 0; j < 8; ++j)
                    cl[ks2][j] = __shfl(cellLocal, ks2 * 32 + quad * 8 + j);

            const int nMt2 = (ncellsW + 15) >> 4;
            _Float16* embT = &sEmb[wid][0];

            auto mfma1_epi = [&](int nt, int slice) {
                f32x4_t acc[4];
#pragma unroll
                for (int mt = 0; mt < 4; ++mt) acc[mt] = (f32x4_t){0.0f, 0.0f, 0.0f, 0.0f};
#pragma unroll
                for (int ks = 0; ks < 3; ++ks) {
                    const half8_t Bf = *(const half8_t*)
                        &sW2T[(nt * 16 + m15) * HSTR + ks * 32 + quad * 8];
#pragma unroll
                    for (int mt = 0; mt < 4; ++mt)
                        acc[mt] = __builtin_amdgcn_mfma_f32_16x16x32_f16(
                            Af[ks][mt], Bf, acc[mt], 0, 0, 0);
                }
                const float bb2 = sb2f[nt * 16 + m15];
#pragma unroll
                for (int mt = 0; mt < 4; ++mt) {
                    const f32x4_t a = acc[mt];
                    half4_t v;
                    v[0] = (_Float16)fmaxf(a[0] + bb2, 0.0f);
                    v[1] = (_Float16)fmaxf(a[1] + bb2, 0.0f);
                    v[2] = (_Float16)fmaxf(a[2] + bb2, 0.0f);
                    v[3] = (_Float16)fmaxf(a[3] + bb2, 0.0f);
                    *(half4_t*)&embT[slice * ESLICE + m15 * ESTR + mt * 16 + quad * 4] = v;
                }
            };

            if (nMt2 == 1) {
                // ======== fast path (<=16 cells): pipelined ========
                half8_t A2h[2];
#pragma unroll
                for (int ks2 = 0; ks2 < 2; ++ks2)
#pragma unroll
                    for (int j = 0; j < 8; ++j)
                        A2h[ks2][j] = (cl[ks2][j] == m15) ? (_Float16)1 : (_Float16)0;
                unsigned int rowr[4];
#pragma unroll
                for (int r = 0; r < 4; ++r) {
                    const int cell = quad * 4 + r;
                    rowr[r] = (cell < ncellsW) ? sCellG[wid][cell] : 0xFFFFFFFFu;
                }

                auto mfma2_store = [&](int nt, int slice) {
                    half8_t B2[2];
#pragma unroll
                    for (int ks2 = 0; ks2 < 2; ++ks2)
                        B2[ks2] = *(const half8_t*)
                            &embT[slice * ESLICE + m15 * ESTR + ks2 * 32 + quad * 8];
                    f32x4_t acc2 = (f32x4_t){0.0f, 0.0f, 0.0f, 0.0f};
#pragma unroll
                    for (int ks2 = 0; ks2 < 2; ++ks2)
                        acc2 = __builtin_amdgcn_mfma_f32_16x16x32_f16(
                            A2h[ks2], B2[ks2], acc2, 0, 0, 0);
                    float* const plane = sums + (size_t)nt * (size_t)P;
#pragma unroll
                    for (int r = 0; r < 4; ++r)
                        if (rowr[r] != 0xFFFFFFFFu)
                            plane[((size_t)rowr[r] << 4) + m15] = acc2[r];
                };

                mfma1_epi(0, 0);
                mfma1_epi(1, 1);
                mfma2_store(0, 0);
                mfma1_epi(2, 0);
                mfma2_store(1, 1);
                mfma1_epi(3, 1);
                mfma2_store(2, 0);
                mfma1_epi(4, 0);
                mfma2_store(3, 1);
                mfma2_store(4, 0);
            } else {
                // ======== general path (>16 cells in chunk) ========
#pragma unroll 1
                for (int nt = 0; nt < 5; ++nt) {
                    mfma1_epi(nt, 0);
                    half8_t B2[2];
#pragma unroll
                    for (int ks2 = 0; ks2 < 2; ++ks2)
                        B2[ks2] = *(const half8_t*)
                            &embT[m15 * ESTR + ks2 * 32 + quad * 8];
                    float* const plane = sums + (size_t)nt * (size_t)P;
                    for (int mt2 = 0; mt2 < nMt2; ++mt2) {
                        const int m2 = mt2 * 16 + m15;
                        f32x4_t acc2 = (f32x4_t){0.0f, 0.0f, 0.0f, 0.0f};
#pragma unroll
                        for (int ks2 = 0; ks2 < 2; ++ks2) {
                            half8_t A2;
#pragma unroll
                            for (int j = 0; j < 8; ++j)
                                A2[j] = (cl[ks2][j] == m2) ? (_Float16)1 : (_Float16)0;
                            acc2 = __builtin_amdgcn_mfma_f32_16x16x32_f16(
                                A2, B2[ks2], acc2, 0, 0, 0);
                        }
#pragma unroll
                        for (int r = 0; r < 4; ++r) {
                            const int cell = mt2 * 16 + quad * 4 + r;
                            if (cell < ncellsW) {
                                const unsigned int row = sCellG[wid][cell];
                                plane[((size_t)row << 4) + m15] = acc2[r];
                            }
                        }
                    }
                }
            }

            if (!hasNext) break;
            wv = wvn; hb = hbN;
#pragma unroll
            for (int mt = 0; mt < 4; ++mt) prm[mt] = prmN[mt];
        }
    }
}

// ---------------------------------------------------------------------------
// Head: half-row blocks — 1024 blocks x 64 cells. LDS 14KB; Wp A-frags
// direct from global (hi/lo f16, L2-hot). Block 0 runs the diagnostics
// beacon.
// ---------------------------------------------------------------------------
__global__ __launch_bounds__(256, 2) void k_head(
    const float* __restrict__ sums,
    const unsigned int* __restrict__ cnt,
    const unsigned int* __restrict__ offs,
    const void* __restrict__ Wp_raw,
    const void* __restrict__ bp_raw,
    const void* __restrict__ gamma_raw,
    const void* __restrict__ beta_raw,
    const void* __restrict__ rmean_raw,
    const void* __restrict__ rvar_raw,
    const unsigned int* __restrict__ flags,
    const unsigned int* __restrict__ magic,
    float* __restrict__ out,
    int b0, int ncells, int P, int hostbits)
{
    __shared__ _Float16 sMean[64 * MSTR];      // [cell64][k], k 80..103 zero
    __shared__ float sAlpha[COUT_], sDelta[COUT_];
    __shared__ float sRedF[4];
    __shared__ unsigned int sRedU[4];

    const int t = threadIdx.x;
    const int blk = blockIdx.x;
    const int bl = blk >> 8;
    const int rem = blk & 255;
    const int hrow = rem >> 1, half = rem & 1;
    const int bg = b0 + bl;
    const int wf32 = (int)flags[0];
    const int lane = t & 63;
    const int wid = t >> 6;
    const int m15 = lane & 15;
    const int quad = lane >> 4;

    if (t < COUT_) {
        if (wf32) {
            const float rs = rsqrtf(((const float*)rvar_raw)[t] + 1e-5f);
            const float al = ((const float*)gamma_raw)[t] * rs;
            sAlpha[t] = al;
            sDelta[t] = al * (((const float*)bp_raw)[t] - ((const float*)rmean_raw)[t])
                        + ((const float*)beta_raw)[t];
        } else {
            const float rs = rsqrtf(bf2f(((const unsigned short*)rvar_raw)[t]) + 1e-5f);
            const float al = bf2f(((const unsigned short*)gamma_raw)[t]) * rs;
            sAlpha[t] = al;
            sDelta[t] = al * (bf2f(((const unsigned short*)bp_raw)[t])
                              - bf2f(((const unsigned short*)rmean_raw)[t]))
                        + bf2f(((const unsigned short*)beta_raw)[t]);
        }
    }

    // ---- A-fragments direct from global (fragment layout, L2-hot), hi/lo.
    half8_t Ahi[2][3], Alo[2][3];
#pragma unroll
    for (int m = 0; m < 2; ++m) {
        const int d = (wid * 2 + m) * 16 + m15;
#pragma unroll
        for (int ks = 0; ks < 3; ++ks) {
#pragma unroll
            for (int j = 0; j < 8; ++j) {
                const int k = ks * 32 + quad * 8 + j;
                float w = 0.0f;
                if (k < CH)
                    w = wf32 ? ((const float*)Wp_raw)[k * COUT_ + d]
                             : bf2f(((const unsigned short*)Wp_raw)[k * COUT_ + d]);
                const _Float16 hi = (_Float16)w;
                Ahi[m][ks][j] = hi;
                Alo[m][ks][j] = (_Float16)(w - (float)hi);
            }
        }
    }

    // ---- stage mean[cell64][k] f16 (+zero pad k 80..103).
    const int cellbase = bl * HW_ + hrow * BEVW + half * 64;
    for (int i = t; i < 64 * 26; i += 256) {
        const int w = i / 26, c4 = i % 26;
        _Float16* m = &sMean[w * MSTR + c4 * 4];
        if (c4 < 20) {
            const int nt = c4 >> 2, q = c4 & 3;
            const int cell = cellbase + w;
            const unsigned int c = cnt[cell];
            float4 s = {0.0f, 0.0f, 0.0f, 0.0f};
            if (c > 0) {
                const float4* plane4 = (const float4*)(sums + (size_t)nt * (size_t)P);
                s = plane4[cell * 4 + q];
                const unsigned int o = offs[cell];
                const int bA = (int)(o >> 6) + 1;
                const int bB = (int)((o + c - 1) >> 6);
                for (int b = bA; b <= bB; ++b) {
                    const float4 st = plane4[(ncells + b) * 4 + q];
                    s.x += st.x; s.y += st.y; s.z += st.z; s.w += st.w;
                }
            }
            const float inv = 1.0f / fmaxf((float)c, 1.0f);
            m[0] = (_Float16)(s.x * inv);
            m[1] = (_Float16)(s.y * inv);
            m[2] = (_Float16)(s.z * inv);
            m[3] = (_Float16)(s.w * inv);
        } else {
            m[0] = (_Float16)0.0f; m[1] = (_Float16)0.0f;
            m[2] = (_Float16)0.0f; m[3] = (_Float16)0.0f;
        }
    }
    __syncthreads();

    float alph[2][4], delt[2][4];
#pragma unroll
    for (int m = 0; m < 2; ++m)
#pragma unroll
        for (int r = 0; r < 4; ++r) {
            const int d = (wid * 2 + m) * 16 + quad * 4 + r;
            alph[m][r] = sAlpha[d];
            delt[m][r] = sDelta[d];
        }

#pragma unroll
    for (int n = 0; n < 4; ++n) {
        half8_t Bf[3];
#pragma unroll
        for (int ks = 0; ks < 3; ++ks)
            Bf[ks] = *(const half8_t*)&sMean[(n * 16 + m15) * MSTR + ks * 32 + quad * 8];
#pragma unroll
        for (int m = 0; m < 2; ++m) {
            f32x4_t acc = (f32x4_t){0.0f, 0.0f, 0.0f, 0.0f};
#pragma unroll
            for (int ks = 0; ks < 3; ++ks) {
                acc = __builtin_amdgcn_mfma_f32_16x16x32_f16(Ahi[m][ks], Bf[ks], acc, 0, 0, 0);
                acc = __builtin_amdgcn_mfma_f32_16x16x32_f16(Alo[m][ks], Bf[ks], acc, 0, 0, 0);
            }
#pragma unroll
            for (int r = 0; r < 4; ++r) {
                const int d = (wid * 2 + m) * 16 + quad * 4 + r;
                float o = fmaxf(fmaf(acc[r], alph[m][r], delt[m][r]), 0.0f);
                o = fminf(o, 512.0f);
                out[(((size_t)bg * COUT_ + d) * BEVH + hrow) * BEVW
                    + half * 64 + n * 16 + m15] = o;
            }
        }
    }

    // ---- diagnostics beacon (block 0 only; healthy run writes nothing).
    if (blk == 0) {
        unsigned int cs = 0;
        for (int i = t; i < HW_; i += 256) cs += cnt[i];
        float sl = 0.0f;
        for (int i = t; i < CH * CH; i += 256) sl += fabsf(sums[i]);
#pragma unroll
        for (int off = 32; off > 0; off >>= 1) {
            cs += __shfl_down(cs, off);
            sl += __shfl_down(sl, off);
        }
        if (lane == 0) { sRedU[wid] = cs; sRedF[wid] = sl; }
        __syncthreads();
        if (t == 0) {
            const unsigned int csum = sRedU[0] + sRedU[1] + sRedU[2] + sRedU[3];
            const float ssum = sRedF[0] + sRedF[1] + sRedF[2] + sRedF[3];
            int code = hostbits;
            if (*magic != 0xCAFEBABEu) code |= 1;
            if (csum < 1000u)          code |= 2;
            if (!(ssum > 0.0f))        code |= 4;
            if (code) {
                code |= (int)(flags[0] ? 32 : 0);
                code |= (int)(flags[1] ? 64 : 0);
                out[0] = 1024.0f * (float)code;
            }
        }
    }
}

extern "C" void kernel_launch(void* const* d_in, const int* in_sizes, int n_in,
                              void* d_out, int out_size, void* d_ws, size_t ws_size,
                              hipStream_t stream) {
    const void* pts   = d_in[0];
    const void* W1    = d_in[1];
    const void* b1    = d_in[2];
    const void* W2    = d_in[3];
    const void* b2    = d_in[4];
    const void* Wp    = d_in[5];
    const void* bp    = d_in[6];
    const void* gamma = d_in[7];
    const void* beta  = d_in[8];
    const void* rmean = d_in[9];
    const void* rvar  = d_in[10];

    int hostbits = 0;
    if (n_in != 11 ||
        in_sizes[0] != B_ * NP_ * 4 ||
        in_sizes[1] != 4 * CH  || in_sizes[2] != CH ||
        in_sizes[3] != CH * CH || in_sizes[4] != CH ||
        in_sizes[5] != CH * COUT_ || in_sizes[6] != COUT_ ||
        out_size != B_ * COUT_ * HW_)
        hostbits |= 8;
    if (ws_size < SCRATCH_OFF + PER_BATCH + EXTRA_BYTES) hostbits |= 16;

    unsigned int* flags = (unsigned int*)d_ws;
    unsigned int* magic = (unsigned int*)((char*)d_ws + MAGIC_OFF);
    char* base = (char*)d_ws + SCRATCH_OFF;
    const size_t avail = (ws_size > SCRATCH_OFF + EXTRA_BYTES)
                       ? (ws_size - SCRATCH_OFF - EXTRA_BYTES) : PER_BATCH;
    int nb = (int)(avail / PER_BATCH);
    if (nb < 1) nb = 1;
    if (nb > B_) nb = B_;

    // Layout: cnt | sums (5 planes, incl. staging rows) | offs(+4) |
    //         chHead | rank | prec (16B-aligned)
    unsigned int*   cnt      = (unsigned int*)base;
    float*          sums     = (float*)(cnt + (size_t)nb * HW_);
    const size_t    sumsFl   = (size_t)5 * ((size_t)nb * HW_ + (size_t)nb * NCHK) * 16;
    unsigned int*   offs     = (unsigned int*)(sums + sumsFl);
    unsigned char*  chHead   = (unsigned char*)(offs + (size_t)nb * HW_ + 4);
    unsigned int*   rank     = (unsigned int*)((char*)chHead
                               + (((size_t)nb * NCHK + 3) & ~(size_t)3));
    char*           palign   = (char*)(rank + (size_t)nb * NP_);
    palign = (char*)(((size_t)palign + 15) & ~(size_t)15);
    uint4*          prec     = (uint4*)palign;

    for (int b0 = 0; b0 < B_; b0 += nb) {
        const int bcnt = (B_ - b0 < nb) ? (B_ - b0) : nb;
        const int ncells = bcnt * HW_;
        const int npts   = bcnt * NP_;
        const int nblk   = ncells >> 10;      // 1024 cells per scan block
        const int P      = (ncells + bcnt * NCHK) * 16;   // plane stride (f32)

        k_init<<<128, 256, 0, stream>>>(
            (float4*)cnt, ncells / 4 + 1600,
            (const unsigned short*)W1, (const unsigned short*)pts, flags);

        k_bin<<<(npts / 2 + 255) / 256, 256, 0, stream>>>(
            pts, flags, cnt, rank, b0, npts);

        k_scan<<<nblk, 256, 0, stream>>>(cnt, offs, chHead, nblk, ncells);

        k_scatteridx<<<(npts / 4 + 255) / 256, 256, 0, stream>>>(
            pts, flags, offs, rank, prec, b0, npts);

        k_mlp_mfma<<<768, 256, 0, stream>>>(
            prec, W1, b1, W2, b2, flags, magic, offs, chHead,
            sums, ncells, P);

        k_head<<<bcnt * BEVH * 2, 256, 0, stream>>>(
            sums, cnt, offs, Wp, bp, gamma, beta, rmean, rvar, flags, magic,
            (float*)d_out, b0, ncells, P, hostbits);
    }
}